// Round 9
// baseline (120.469 us; speedup 1.0000x reference)
//
#include <hip/hip_runtime.h>
#include <math.h>

#define NB 8192
#define DK 128
#define RT 128             // rows per block
#define CW 512             // cols per block (chunk)
#define NCW 16             // col chunks
#define NBLK 544           // sum_{u=0}^{15} 4*(16-u): blocks (bi,c) with c >= bi>>2
#define JT 64              // cols per LDS tile
#define NT (CW / JT)       // 8 j-tiles per block
#define BSTRH 136          // B LDS row stride in bf16 (272 B) -> 0 conflicts (measured)
#define NSLOT 80           // 16 row-side slots (by chunk c) + 64 col-side (by row-tile bi)
#define SENT -1.7e38f

typedef __attribute__((ext_vector_type(8))) short short8;
typedef __attribute__((ext_vector_type(16))) float float16;

__device__ inline unsigned short f2bf(float f) {
    unsigned int x = __float_as_uint(f);
    unsigned int r = (x + 0x7fffu + ((x >> 16) & 1u)) >> 16;
    return (unsigned short)r;
}

// ---- normalize -> bf16, packed meta, sentinel-fill partials, zero accum -------
__global__ void norm_kernel(const float* __restrict__ emb, const int* __restrict__ labels,
                            const int* __restrict__ groups, unsigned short* __restrict__ xnb,
                            int* __restrict__ meta, float2* __restrict__ part,
                            float* __restrict__ accum, int* __restrict__ ticket) {
    int row  = blockIdx.x * 4 + (threadIdx.x >> 6);
    int lane = threadIdx.x & 63;
    float2 v = ((const float2*)(emb + (size_t)row * DK))[lane];
    float ss = v.x * v.x + v.y * v.y;
#pragma unroll
    for (int off = 32; off; off >>= 1) ss += __shfl_xor(ss, off, 64);
    float inv = 1.0f / fmaxf(sqrtf(ss), 1e-12f);
    ushort2 o;
    o.x = f2bf(v.x * inv);
    o.y = f2bf(v.y * inv);
    ((ushort2*)(xnb + (size_t)row * DK))[lane] = o;
    if (lane == 0) meta[row] = (labels[row] << 8) | groups[row];

    // sentinel-fill part[80][NB]: 655360 float2 over 524288 threads
    size_t g = (size_t)blockIdx.x * 256 + threadIdx.x;
    float2 snt; snt.x = SENT; snt.y = SENT;
    part[g] = snt;
    if (g < (size_t)NSLOT * NB - 524288) part[g + 524288] = snt;

    if (blockIdx.x == 0 && threadIdx.x == 0) {
        accum[0] = 0.0f; accum[1] = 0.0f; ticket[0] = 0;
    }
}

// ---- chunk-triangular MFMA gram + two-sided mining ----------------------------
// R0's proven block shape (128x512, 8 double-buffered 64-col tiles, 128 MFMA/wave)
// launched only for (bi, c) with c >= bi>>2 (0.53x work). Coverage: row-quad
// (512 rows) == chunk width, so for any pair (i,j): c_j >= c_i or c_i >= c_j,
// i.e. every pair appears in some block as (row,col) or (col,row).
//
// Encoded similarity space (proven):  -t = (sl?8:0) - s ;  v = s - 8*sl + 4*sg
// C layout (verified): col = lane&31, row = (reg&3) + 8*(reg>>2) + 4*(lane>>5)
// part slots: [c]      row-side: anchors = block rows, over 512 cols of chunk c
//             [16+bi]  col-side: anchors = chunk cols, over 128 rows of tile bi
// Each (slot,anchor) has exactly one writer; invalid slots hold SENT.
// Uncapped launch bounds: (256,3) caps arch VGPR at 84 -> ~31-reg spill (r4/r6).
__global__ __launch_bounds__(256) void mine_rt(
    const unsigned short* __restrict__ xnb, const int* __restrict__ meta,
    float2* __restrict__ part) {
    __shared__ unsigned short Bs[2][JT * BSTRH];   // 2 x 17408 B
    __shared__ float colred[2][4][16][32];         // 16 KB: [arr][wave][qq][col]

    // decode blockIdx.x -> (bi, c): quad u = bi>>2 has 4*(16-u) blocks
    int bid = blockIdx.x;
    int u = 0;
    while (bid >= 4 * (NCW - u)) { bid -= 4 * (NCW - u); u++; }
    const int cnt = NCW - u;
    const int bi  = 4 * u + bid / cnt;
    const int c   = u + bid % cnt;

    const int tid  = threadIdx.x;
    const int w    = tid >> 6;
    const int lane = tid & 63;
    const int half = lane >> 5;
    const int l31  = lane & 31;
    const int jbase = c * CW;
    const int irow  = bi * RT + w * 32;

    // A fragments, full K=128 resident (8 x short8 = 64 VGPRs)
    short8 afrag[8];
#pragma unroll
    for (int ks = 0; ks < 8; ks++)
        afrag[ks] = *(const short8*)(xnb + (size_t)(irow + l31) * DK + ks * 16 + half * 8);

    int metaI[16];
    float apn[16], anc[16];
#pragma unroll
    for (int reg = 0; reg < 16; reg++) {
        int r = (reg & 3) + 8 * (reg >> 2) + 4 * half;
        metaI[reg] = meta[irow + r];
        apn[reg] = -1e9f; anc[reg] = -1e9f;
    }

    // prologue: stage tile 0 (rows jbase .. jbase+63)
#pragma unroll
    for (int s = 0; s < 4; s++) {
        int chunk = tid + s * 256;
        int row = chunk >> 4, k4 = chunk & 15;
        *(uint4*)&Bs[0][row * BSTRH + k4 * 8] =
            *(const uint4*)(xnb + (size_t)(jbase + row) * DK + k4 * 8);
    }
    __syncthreads();

    for (int jt = 0; jt < NT; jt++) {
        const int cur = jt & 1;
        const int j0  = jbase + jt * JT;

        // prefetch next tile into registers (overlaps with compute below)
        uint4 pre[4];
        if (jt + 1 < NT) {
            const int j0n = j0 + JT;
#pragma unroll
            for (int s = 0; s < 4; s++) {
                int chunk = tid + s * 256;
                int row = chunk >> 4, k4 = chunk & 15;
                pre[s] = *(const uint4*)(xnb + (size_t)(j0n + row) * DK + k4 * 8);
            }
        }

        int mjc[2];
        mjc[0] = meta[j0 + l31];
        mjc[1] = meta[j0 + 32 + l31];

#pragma unroll
        for (int ct = 0; ct < 2; ct++) {
            float16 cc;
#pragma unroll
            for (int e = 0; e < 16; e++) cc[e] = 0.0f;

            const int bro = ct * 32 + l31;
#pragma unroll
            for (int ks = 0; ks < 8; ks++) {
                short8 b = *(const short8*)&Bs[cur][bro * BSTRH + ks * 16 + half * 8];
                cc = __builtin_amdgcn_mfma_f32_32x32x16_bf16(afrag[ks], b, cc, 0, 0, 0);
            }

            const int mj = mjc[ct];
            float ca = -1e9f, cn = -1e9f;          // col-side, transient (2 regs)
#pragma unroll
            for (int reg = 0; reg < 16; reg++) {
                float s = cc[reg];
                int x = metaI[reg] ^ mj;
                bool sl = (unsigned)x < 0x100u;    // same label
                float t8 = s - 8.0f;
                float t  = sl ? t8 : s;            // t = s - (sl?8:0)
                float negt = -t;
                apn[reg] = fmaxf(apn[reg], negt);  // row-side (anchor = i)
                ca = fmaxf(ca, negt);              // col-side (anchor = j)
                bool sg = (x & 0xFFu) == 0u;       // same group
                float t4 = t + 4.0f;
                float v  = sg ? t4 : t;            // + (sg?4:0)
                anc[reg] = fmaxf(anc[reg], v);
                cn = fmaxf(cn, v);
            }
            // fold halves, park in LDS (wave-private slice; no barrier needed)
            ca = fmaxf(ca, __shfl_xor(ca, 32, 64));
            cn = fmaxf(cn, __shfl_xor(cn, 32, 64));
            if (half == 0) {
                colred[0][w][jt * 2 + ct][l31] = ca;
                colred[1][w][jt * 2 + ct][l31] = cn;
            }
        }

        // write prefetched tile into the other buffer
        if (jt + 1 < NT) {
#pragma unroll
            for (int s = 0; s < 4; s++) {
                int chunk = tid + s * 256;
                int row = chunk >> 4, k4 = chunk & 15;
                *(uint4*)&Bs[cur ^ 1][row * BSTRH + k4 * 8] = pre[s];
            }
        }
        __syncthreads();
    }

    // ---- row side: butterfly reduce across the 32 column-lanes, slot c ----
#pragma unroll
    for (int reg = 0; reg < 16; reg++) {
#pragma unroll
        for (int off = 16; off; off >>= 1) {
            apn[reg] = fmaxf(apn[reg], __shfl_xor(apn[reg], off, 64));
            anc[reg] = fmaxf(anc[reg], __shfl_xor(anc[reg], off, 64));
        }
    }
    if (l31 == 0) {
#pragma unroll
        for (int reg = 0; reg < 16; reg++) {
            int r = (reg & 3) + 8 * (reg >> 2) + 4 * half;
            float2 o; o.x = apn[reg]; o.y = anc[reg];
            part[(size_t)c * NB + (irow + r)] = o;
        }
    }

    // ---- col side: cross-wave reduce of colred, slot 16+bi (512 cols) ----
    // (last jt iteration ended with __syncthreads -> all colred writes visible)
#pragma unroll
    for (int k = 0; k < 2; k++) {
        int item = tid + k * 256;                  // qq*32 + col, 0..511
        int qq = item >> 5, col = item & 31;
        float ma = -1e9f, mn = -1e9f;
#pragma unroll
        for (int wv = 0; wv < 4; wv++) {
            ma = fmaxf(ma, colred[0][wv][qq][col]);
            mn = fmaxf(mn, colred[1][wv][qq][col]);
        }
        float2 o; o.x = ma; o.y = mn;
        part[(size_t)(NCW + bi) * NB + (jbase + item)] = o;
    }
}

// ---- combine: 80 static slots per anchor + ticketed finalize ------------------
__global__ void combine_kernel(const float2* __restrict__ part,
                               float* __restrict__ accum, int* __restrict__ ticket,
                               float* __restrict__ out) {
    int i = blockIdx.x * 256 + threadIdx.x;
    float a0 = -3e38f, a1 = -3e38f, a2 = -3e38f, a3 = -3e38f;
    float n0 = -3e38f, n1 = -3e38f, n2 = -3e38f, n3 = -3e38f;
#pragma unroll
    for (int s = 0; s < NSLOT; s += 4) {
        float2 p0 = part[(size_t)(s + 0) * NB + i];
        float2 p1 = part[(size_t)(s + 1) * NB + i];
        float2 p2 = part[(size_t)(s + 2) * NB + i];
        float2 p3 = part[(size_t)(s + 3) * NB + i];
        a0 = fmaxf(a0, p0.x); n0 = fmaxf(n0, p0.y);
        a1 = fmaxf(a1, p1.x); n1 = fmaxf(n1, p1.y);
        a2 = fmaxf(a2, p2.x); n2 = fmaxf(n2, p2.y);
        a3 = fmaxf(a3, p3.x); n3 = fmaxf(n3, p3.y);
    }
    float apn = fmaxf(fmaxf(a0, a1), fmaxf(a2, a3));
    float anc = fmaxf(fmaxf(n0, n1), fmaxf(n2, n3));

    float anS = (anc > 2.0f) ? anc - 4.0f : anc;
    // loss = anS - (8 - apn) + 0.1 ; suppressed-label values decode to loss <= 0
    float loss = anS + apn - 7.9f;
    float inc = (loss > 0.0f) ? 1.0f : 0.0f;
    float val = inc * loss;

    __shared__ float ssum[4], scnt[4];
#pragma unroll
    for (int off = 32; off; off >>= 1) {
        val += __shfl_xor(val, off, 64);
        inc += __shfl_xor(inc, off, 64);
    }
    int wid = threadIdx.x >> 6, lane = threadIdx.x & 63;
    if (lane == 0) { ssum[wid] = val; scnt[wid] = inc; }
    __syncthreads();
    if (threadIdx.x == 0) {
        float s = 0.f, cfc = 0.f;
#pragma unroll
        for (int wv = 0; wv < 4; wv++) { s += ssum[wv]; cfc += scnt[wv]; }
        atomicAdd(&accum[0], s);
        atomicAdd(&accum[1], cfc);
        __threadfence();                       // release: accum adds visible device-wide
        int old = atomicAdd(ticket, 1);        // device-scope
        if (old == gridDim.x - 1) {            // last block finalizes
            __threadfence();                   // acquire side
            float total = __hip_atomic_load(&accum[0], __ATOMIC_RELAXED, __HIP_MEMORY_SCOPE_AGENT);
            float cnt   = __hip_atomic_load(&accum[1], __ATOMIC_RELAXED, __HIP_MEMORY_SCOPE_AGENT);
            float r = (cnt > 0.0f) ? total / fmaxf(cnt, 1.0f) : 0.0f;
            if (isnan(r)) r = 0.0f;
            out[0] = r;
        }
    }
}

extern "C" void kernel_launch(void* const* d_in, const int* in_sizes, int n_in,
                              void* d_out, int out_size, void* d_ws, size_t ws_size,
                              hipStream_t stream) {
    const float* emb  = (const float*)d_in[0];
    const int* labels = (const int*)d_in[1];
    const int* groups = (const int*)d_in[2];
    float* out = (float*)d_out;

    unsigned short* xnb = (unsigned short*)d_ws;            // 2 MB
    int*    meta   = (int*)(xnb + (size_t)NB * DK);         // 32 KB
    float2* part   = (float2*)(meta + NB);                  // 5.25 MB: [80][NB]
    float*  accum  = (float*)(part + (size_t)NSLOT * NB);   // 2 floats
    int*    ticket = (int*)(accum + 2);                     // 1 int

    norm_kernel<<<NB / 4, 256, 0, stream>>>(emb, labels, groups, xnb, meta, part, accum, ticket);
    mine_rt<<<NBLK, 256, 0, stream>>>(xnb, meta, part);
    combine_kernel<<<NB / 256, 256, 0, stream>>>(part, accum, ticket, out);
}

// Round 10
// 99.839 us; speedup vs baseline: 1.2066x; 1.2066x over previous
//
#include <hip/hip_runtime.h>
#include <math.h>

#define NB 8192
#define DK 128
#define IT 128              // i-rows per block (4 waves x 32)
#define JT 64               // j-cols per LDS tile
#define SPLITJ 16
#define JSPAN (NB / SPLITJ) // 512
#define NT (JSPAN / JT)     // 8 j-tiles per block
#define BSTRH 136           // B LDS row stride in bf16 (272 B) -> conflict-free b128
#define NCOMB (NB / 256)    // 32 combine blocks

typedef __attribute__((ext_vector_type(8))) short short8;
typedef __attribute__((ext_vector_type(16))) float float16;

__device__ inline unsigned short f2bf(float f) {
    unsigned int x = __float_as_uint(f);
    unsigned int r = (x + 0x7fffu + ((x >> 16) & 1u)) >> 16;
    return (unsigned short)r;
}

// ---------------- normalize -> bf16, packed meta, zero accum/ticket ----------
// (accum/ticket zeroing folded in from the old hipMemsetAsync: one fewer graph
//  dispatch; ordering is stream-sequential so combine sees zeroed state)
__global__ void norm_kernel(const float* __restrict__ emb, const int* __restrict__ labels,
                            const int* __restrict__ groups, unsigned short* __restrict__ xnb,
                            int* __restrict__ meta, float* __restrict__ accum,
                            int* __restrict__ ticket) {
    int row  = blockIdx.x * 4 + (threadIdx.x >> 6);
    int lane = threadIdx.x & 63;
    float2 v = ((const float2*)(emb + (size_t)row * DK))[lane];
    float ss = v.x * v.x + v.y * v.y;
#pragma unroll
    for (int off = 32; off; off >>= 1) ss += __shfl_xor(ss, off, 64);
    float inv = 1.0f / fmaxf(sqrtf(ss), 1e-12f);
    ushort2 o;
    o.x = f2bf(v.x * inv);
    o.y = f2bf(v.y * inv);
    ((ushort2*)(xnb + (size_t)row * DK))[lane] = o;
    if (lane == 0) meta[row] = (labels[row] << 8) | groups[row];
    if (blockIdx.x == 0 && threadIdx.x == 0) {
        accum[0] = 0.0f; accum[1] = 0.0f; ticket[0] = 0;
    }
}

// ---------------- fused MFMA gram + hard mining (encoded similarity space) ----
// apn = max over all j of ( (same_label? 8:0) - s )   ->  apS = 8 - apn (if apn>2)
// anc = max over all j of ( s - (same_label? 8:0) + (same_group? 4:0) )
//   diff&sg: s+4 in [3,5] ; diff&!sg: s in [-1,1] ; suppressed <= -3.
//   decode: anS = anc>2 ? anc-4 : anc ; has_neg <=> anc > -2.
// C layout (verified): col = lane&31, row = (reg&3) + 8*(reg>>2) + 4*(lane>>5)
//
// NOTE: this is the round-0 proven configuration, byte-identical. Session
// post-mortems (r2-r9): six symmetry/triangle variants all lost to allocator
// spills ((256,3) caps arch VGPR ~84 when pressure grows past R0's), exposed
// stage latency, or sub-occupancy grids. MfmaUtil is 6-7% in every clean
// profile -> the kernel is mining-VALU/staging-bound, so halving MFMA FLOPs
// has no headroom to pay for its structural taxes. Do not re-litigate without
// first fixing the allocator behavior.
__global__ __launch_bounds__(256, 3) void mine_mfma(
    const unsigned short* __restrict__ xnb, const int* __restrict__ meta,
    float* __restrict__ ap_part, float* __restrict__ an_part) {
    __shared__ unsigned short Bs[2][JT * BSTRH];   // 2 x 17408 B

    const int tid  = threadIdx.x;
    const int w    = tid >> 6;
    const int lane = tid & 63;
    const int half = lane >> 5;
    const int l31  = lane & 31;
    const int i0    = blockIdx.x * IT;
    const int jbase = blockIdx.y * JSPAN;
    const int irow  = i0 + w * 32;

    // A fragments, full K=128 resident (8 x short8 = 64 VGPRs)
    short8 afrag[8];
#pragma unroll
    for (int ks = 0; ks < 8; ks++)
        afrag[ks] = *(const short8*)(xnb + (size_t)(irow + l31) * DK + ks * 16 + half * 8);

    int metaI[16];
    float apn[16], anc[16];
#pragma unroll
    for (int reg = 0; reg < 16; reg++) {
        int r = (reg & 3) + 8 * (reg >> 2) + 4 * half;
        metaI[reg] = meta[irow + r];
        apn[reg] = -1e9f; anc[reg] = -1e9f;
    }

    // prologue: stage tile 0
#pragma unroll
    for (int s = 0; s < 4; s++) {
        int chunk = tid + s * 256;
        int row = chunk >> 4, k4 = chunk & 15;
        *(uint4*)&Bs[0][row * BSTRH + k4 * 8] =
            *(const uint4*)(xnb + (size_t)(jbase + row) * DK + k4 * 8);
    }
    __syncthreads();

    for (int jt = 0; jt < NT; jt++) {
        const int cur = jt & 1;
        const int j0  = jbase + jt * JT;

        // prefetch next tile into registers (overlaps with compute below)
        uint4 pre[4];
        if (jt + 1 < NT) {
            const int j0n = j0 + JT;
#pragma unroll
            for (int s = 0; s < 4; s++) {
                int chunk = tid + s * 256;
                int row = chunk >> 4, k4 = chunk & 15;
                pre[s] = *(const uint4*)(xnb + (size_t)(j0n + row) * DK + k4 * 8);
            }
        }

        int mjc[2];
        mjc[0] = meta[j0 + l31];
        mjc[1] = meta[j0 + 32 + l31];

#pragma unroll
        for (int ct = 0; ct < 2; ct++) {
            float16 c;
#pragma unroll
            for (int e = 0; e < 16; e++) c[e] = 0.0f;

            const int bro = ct * 32 + l31;
#pragma unroll
            for (int ks = 0; ks < 8; ks++) {
                short8 b = *(const short8*)&Bs[cur][bro * BSTRH + ks * 16 + half * 8];
                c = __builtin_amdgcn_mfma_f32_32x32x16_bf16(afrag[ks], b, c, 0, 0, 0);
            }

            const int mj = mjc[ct];
#pragma unroll
            for (int reg = 0; reg < 16; reg++) {
                float s = c[reg];
                int x = metaI[reg] ^ mj;
                bool sl = (unsigned)x < 0x100u;     // same label
                float t8 = s - 8.0f;
                float t  = sl ? t8 : s;             // t = s - (sl?8:0)
                apn[reg] = fmaxf(apn[reg], -t);     // neg modifier: free
                bool sg = (x & 0xFFu) == 0u;        // same group
                float t4 = t + 4.0f;
                float v  = sg ? t4 : t;             // + (sg?4:0)
                anc[reg] = fmaxf(anc[reg], v);
            }
        }

        // write prefetched tile into the other buffer
        if (jt + 1 < NT) {
#pragma unroll
            for (int s = 0; s < 4; s++) {
                int chunk = tid + s * 256;
                int row = chunk >> 4, k4 = chunk & 15;
                *(uint4*)&Bs[cur ^ 1][row * BSTRH + k4 * 8] = pre[s];
            }
        }
        __syncthreads();
    }

    // butterfly reduce across the 32 column-lanes (offsets < 32 stay in-half)
#pragma unroll
    for (int reg = 0; reg < 16; reg++) {
#pragma unroll
        for (int off = 16; off; off >>= 1) {
            apn[reg] = fmaxf(apn[reg], __shfl_xor(apn[reg], off, 64));
            anc[reg] = fmaxf(anc[reg], __shfl_xor(anc[reg], off, 64));
        }
    }
    if (l31 == 0) {
#pragma unroll
        for (int reg = 0; reg < 16; reg++) {
            int r = (reg & 3) + 8 * (reg >> 2) + 4 * half;
            size_t idx = (size_t)blockIdx.y * NB + (irow + r);
            ap_part[idx] = apn[reg];
            an_part[idx] = anc[reg];
        }
    }
}

// ---------------- combine partials + ticketed finalize (fused) ----------------
__global__ void combine_kernel(const float* __restrict__ ap_part,
                               const float* __restrict__ an_part,
                               float* __restrict__ accum, int* __restrict__ ticket,
                               float* __restrict__ out) {
    int i = blockIdx.x * 256 + threadIdx.x;
    float apn = -1e9f, anc = -1e9f;
#pragma unroll
    for (int h = 0; h < SPLITJ; h++) {
        size_t idx = (size_t)h * NB + i;
        apn = fmaxf(apn, ap_part[idx]);
        anc = fmaxf(anc, an_part[idx]);
    }
    float anS = (anc > 2.0f) ? anc - 4.0f : anc;
    // loss = anS - (8 - apn) + 0.1 ; sentinels: no-pos apn<=1.02, no-neg anS<=-2.98
    float loss = anS + apn - 7.9f;
    float inc = (loss > 0.0f) ? 1.0f : 0.0f;
    float val = inc * loss;

    __shared__ float ssum[4], scnt[4];
#pragma unroll
    for (int off = 32; off; off >>= 1) {
        val += __shfl_xor(val, off, 64);
        inc += __shfl_xor(inc, off, 64);
    }
    int wid = threadIdx.x >> 6, lane = threadIdx.x & 63;
    if (lane == 0) { ssum[wid] = val; scnt[wid] = inc; }
    __syncthreads();
    if (threadIdx.x == 0) {
        float s = 0.f, c = 0.f;
#pragma unroll
        for (int wv = 0; wv < 4; wv++) { s += ssum[wv]; c += scnt[wv]; }
        atomicAdd(&accum[0], s);
        atomicAdd(&accum[1], c);
        __threadfence();                       // release: accum adds visible device-wide
        int old = atomicAdd(ticket, 1);        // device-scope
        if (old == gridDim.x - 1) {            // last block finalizes
            __threadfence();                   // acquire side
            float total = __hip_atomic_load(&accum[0], __ATOMIC_RELAXED, __HIP_MEMORY_SCOPE_AGENT);
            float cnt   = __hip_atomic_load(&accum[1], __ATOMIC_RELAXED, __HIP_MEMORY_SCOPE_AGENT);
            float r = (cnt > 0.0f) ? total / fmaxf(cnt, 1.0f) : 0.0f;
            if (isnan(r)) r = 0.0f;
            out[0] = r;
        }
    }
}

extern "C" void kernel_launch(void* const* d_in, const int* in_sizes, int n_in,
                              void* d_out, int out_size, void* d_ws, size_t ws_size,
                              hipStream_t stream) {
    const float* emb  = (const float*)d_in[0];
    const int* labels = (const int*)d_in[1];
    const int* groups = (const int*)d_in[2];
    float* out = (float*)d_out;

    unsigned short* xnb = (unsigned short*)d_ws;            // 2 MB
    int*   meta    = (int*)(xnb + (size_t)NB * DK);         // 32 KB
    float* ap_part = (float*)(meta + NB);
    float* an_part = ap_part + (size_t)SPLITJ * NB;
    float* accum   = an_part + (size_t)SPLITJ * NB;         // 2 floats
    int*   ticket  = (int*)(accum + 2);                     // 1 int

    norm_kernel<<<NB / 4, 256, 0, stream>>>(emb, labels, groups, xnb, meta, accum, ticket);
    mine_mfma<<<dim3(NB / IT, SPLITJ), 256, 0, stream>>>(
        xnb, meta, ap_part, an_part);
    combine_kernel<<<NCOMB, 256, 0, stream>>>(ap_part, an_part, accum, ticket, out);
}